// Round 1
// baseline (244.096 us; speedup 1.0000x reference)
//
#include <hip/hip_runtime.h>
#include <float.h>

#define H        400
#define W_CROP   400
#define PSF_W    121
#define MARGIN   44
#define IM       488
#define NZ       64
#define N_EMIT   2048
#define PSF_AREA (PSF_W * PSF_W)     /* 14641 */
#define CANVAS_AREA (IM * IM)        /* 238144 */
#define SIGMA2   100.0f              /* SIGMA_READ^2 */

static __device__ __forceinline__ unsigned enc_ord(float f) {
    unsigned u = __float_as_uint(f);
    return (u & 0x80000000u) ? ~u : (u | 0x80000000u);
}
static __device__ __forceinline__ float dec_ord(unsigned u) {
    return __uint_as_float((u & 0x80000000u) ? (u & 0x7fffffffu) : ~u);
}

__global__ void zero_kernel(float* __restrict__ canvas, unsigned* __restrict__ minmax) {
    int i = blockIdx.x * 256 + threadIdx.x;
    if (i < CANVAS_AREA) canvas[i] = 0.0f;
    if (i == 0) { minmax[0] = 0xFFFFFFFFu; /* +inf encoded-min slot */ minmax[1] = 0u; }
}

__global__ __launch_bounds__(256) void splat_kernel(
        const float* __restrict__ xyz,      /* (N_EMIT,3) */
        const float* __restrict__ nph_arr,  /* (N_EMIT)   */
        const float* __restrict__ psf_bank, /* (NZ,121,121) */
        float* __restrict__ canvas)         /* (IM,IM) */
{
    __shared__ float shbuf[PSF_AREA];
    __shared__ float red[4];

    const int e = blockIdx.x;
    const float x = xyz[3 * e + 0];
    const float y = xyz[3 * e + 1];
    const float z = xyz[3 * e + 2];
    const float nph = nph_arr[e];

    int zi = (int)rintf((z + 2.0f) / 4.0f * 63.0f);
    zi = min(max(zi, 0), NZ - 1);

    const float lx = (x * 100.0f) / 11.0f;
    const float ly = (y * 100.0f) / 11.0f;
    const float r0f = (ly + 244.0f) - 60.5f;   /* IM/2 - PSF_W/2 */
    const float c0f = (lx + 244.0f) - 60.5f;
    const int   r0 = (int)floorf(r0f);
    const int   c0 = (int)floorf(c0f);
    const float rs = r0f - floorf(r0f);
    const float cs = c0f - floorf(c0f);

    const float w00 = (1.0f - rs) * (1.0f - cs); /* psf[r  ][c  ] */
    const float w10 = rs * (1.0f - cs);          /* psf[r-1][c  ] */
    const float w01 = (1.0f - rs) * cs;          /* psf[r  ][c-1] */
    const float w11 = rs * cs;                   /* psf[r-1][c-1] */

    const float* __restrict__ psf = psf_bank + (size_t)zi * PSF_AREA;

    float partial = 0.0f;
    for (int i = threadIdx.x; i < PSF_AREA; i += 256) {
        const int r = i / PSF_W;
        const int c = i - r * PSF_W;
        float v = w00 * psf[i];
        if (r > 0)          v += w10 * psf[i - PSF_W];
        if (c > 0)          v += w01 * psf[i - 1];
        if (r > 0 && c > 0) v += w11 * psf[i - PSF_W - 1];
        v = fabsf(v);
        shbuf[i] = v;
        partial += v;
    }

    /* block reduce sum */
    #pragma unroll
    for (int off = 32; off > 0; off >>= 1)
        partial += __shfl_down(partial, off, 64);
    const int wave = threadIdx.x >> 6;
    const int lane = threadIdx.x & 63;
    if (lane == 0) red[wave] = partial;
    __syncthreads();
    const float total = red[0] + red[1] + red[2] + red[3];
    const float scale = nph / total;

    const int base = r0 * IM + c0;
    for (int i = threadIdx.x; i < PSF_AREA; i += 256) {
        const int r = i / PSF_W;
        const int c = i - r * PSF_W;
        atomicAdd(&canvas[base + r * IM + c], shbuf[i] * scale);
    }
}

static __device__ __forceinline__ float noisy_val(const float* __restrict__ canvas,
                                                  const float* __restrict__ noise,
                                                  int i) {
    const int r = i / W_CROP;
    const int c = i - r * W_CROP;
    const float im = canvas[(r + MARGIN) * IM + (c + MARGIN)];
    return im + sqrtf(fmaxf(im, 0.0f) + SIGMA2) * noise[i];
}

__global__ __launch_bounds__(256) void minmax_kernel(
        const float* __restrict__ canvas,
        const float* __restrict__ noise,
        unsigned* __restrict__ minmax)
{
    const int i = blockIdx.x * 256 + threadIdx.x;   /* grid exactly covers 400*400 */
    float v = noisy_val(canvas, noise, i);
    float vmin = v, vmax = v;
    #pragma unroll
    for (int off = 32; off > 0; off >>= 1) {
        vmin = fminf(vmin, __shfl_down(vmin, off, 64));
        vmax = fmaxf(vmax, __shfl_down(vmax, off, 64));
    }
    if ((threadIdx.x & 63) == 0) {
        atomicMin(&minmax[0], enc_ord(vmin));
        atomicMax(&minmax[1], enc_ord(vmax));
    }
}

__global__ __launch_bounds__(256) void finalize_kernel(
        const float* __restrict__ canvas,
        const float* __restrict__ noise,
        const unsigned* __restrict__ minmax,
        float* __restrict__ out)
{
    const int i = blockIdx.x * 256 + threadIdx.x;
    const float v = noisy_val(canvas, noise, i);
    const float mn = dec_ord(minmax[0]);
    const float mx = dec_ord(minmax[1]);
    out[i] = (v - mn) / (mx - mn);
}

extern "C" void kernel_launch(void* const* d_in, const int* in_sizes, int n_in,
                              void* d_out, int out_size, void* d_ws, size_t ws_size,
                              hipStream_t stream) {
    const float* xyz      = (const float*)d_in[0];  /* (1,2048,3) */
    const float* nph      = (const float*)d_in[1];  /* (1,2048)   */
    /* d_in[2] = xy_center, unused by reference */
    const float* psf_bank = (const float*)d_in[3];  /* (64,121,121) */
    const float* noise    = (const float*)d_in[4];  /* (400,400) */
    float* out = (float*)d_out;

    float* canvas = (float*)d_ws;
    unsigned* minmax = (unsigned*)((char*)d_ws + (size_t)CANVAS_AREA * sizeof(float));

    const int npix = H * W_CROP;                 /* 160000 = 625 * 256 */
    zero_kernel<<<(CANVAS_AREA + 255) / 256, 256, 0, stream>>>(canvas, minmax);
    splat_kernel<<<N_EMIT, 256, 0, stream>>>(xyz, nph, psf_bank, canvas);
    minmax_kernel<<<npix / 256, 256, 0, stream>>>(canvas, noise, minmax);
    finalize_kernel<<<npix / 256, 256, 0, stream>>>(canvas, noise, minmax, out);
}